// Round 3
// baseline (117.890 us; speedup 1.0000x reference)
//
#include <hip/hip_runtime.h>
#include <hip/hip_fp16.h>

#define GYD 512
#define GXD 512
#define HD 256
#define WD 256
#define BD 8
#define NSAMP 100000
#define JD 7
#define NCP 9           // padded LDS stride in float2 elements (8 batches + 1)
#define SPB 64          // gather: samples per block

// digit-reverse base 8, 3 digits (involution)
__device__ __forceinline__ int dr3(int i) {
    return ((i & 7) << 6) | (i & 56) | ((i >> 6) & 7);
}

// One radix-8 DIT stage over 8 interleaved 512-pt FFTs in LDS.
// Complex-interleaved float2 LDS: ds_read_b64/ds_write_b64 -- half the DS
// instruction count of the separate re[]/im[] version, identical arithmetic.
// ZHI: inputs j=4..7 structurally zero (zero-padded upper half, stage 1 only).
template<int LEN, int EIGHTH, int TWSH, bool ZHI>
__device__ __forceinline__ void r8_stage(float2* __restrict__ cx,
                                         const float2* __restrict__ tw, int g) {
    const int c = g & 7;
    const int m = g >> 3;
    const int off = m & (EIGHTH - 1);
    const int blk = m / EIGHTH;
    const int p0 = (blk * LEN + off) * NCP + c;

    float E0r, E0i, E1r, E1i, E2r, E2i, E3r, E3i;
    float O0r, O0i, O1r, O1i, O2r, O2i, O3r, O3i;

    if (ZHI) {
        // a4..a7 == 0: evens reduce to {a0,a2}, odds to {a1,a3}.
        const float2 a0 = cx[p0 + 0 * EIGHTH * NCP];
        const float2 a1 = cx[p0 + 1 * EIGHTH * NCP];
        const float2 a2 = cx[p0 + 2 * EIGHTH * NCP];
        const float2 a3 = cx[p0 + 3 * EIGHTH * NCP];
        E0r = a0.x + a2.x; E0i = a0.y + a2.y;
        E2r = a0.x - a2.x; E2i = a0.y - a2.y;
        E1r = a0.x + a2.y; E1i = a0.y - a2.x;     // a0 - i*a2
        E3r = a0.x - a2.y; E3i = a0.y + a2.x;     // a0 + i*a2
        O0r = a1.x + a3.x; O0i = a1.y + a3.y;
        O2r = a1.x - a3.x; O2i = a1.y - a3.y;
        O1r = a1.x + a3.y; O1i = a1.y - a3.x;     // a1 - i*a3
        O3r = a1.x - a3.y; O3i = a1.y + a3.x;     // a1 + i*a3
    } else {
        float ar[8], ai[8];
        #pragma unroll
        for (int j = 0; j < 8; ++j) {
            const float2 v = cx[p0 + j * EIGHTH * NCP];
            ar[j] = v.x;
            ai[j] = v.y;
        }
        if (TWSH >= 0) {
            #pragma unroll
            for (int j = 1; j < 8; ++j) {
                const int idx = (off * j) << (TWSH >= 0 ? TWSH : 0);
                const float2 w = tw[idx];
                const float tr = ar[j] * w.x - ai[j] * w.y;
                ai[j] = ar[j] * w.y + ai[j] * w.x;
                ar[j] = tr;
            }
        }
        const float e0r = ar[0] + ar[4], e0i = ai[0] + ai[4];
        const float e1r = ar[0] - ar[4], e1i = ai[0] - ai[4];
        const float e2r = ar[2] + ar[6], e2i = ai[2] + ai[6];
        const float e3r = ar[2] - ar[6], e3i = ai[2] - ai[6];
        E0r = e0r + e2r; E0i = e0i + e2i;
        E2r = e0r - e2r; E2i = e0i - e2i;
        E1r = e1r + e3i; E1i = e1i - e3r;     // e1 - i*e3
        E3r = e1r - e3i; E3i = e1i + e3r;     // e1 + i*e3

        const float q0r = ar[1] + ar[5], q0i = ai[1] + ai[5];
        const float q1r = ar[1] - ar[5], q1i = ai[1] - ai[5];
        const float q2r = ar[3] + ar[7], q2i = ai[3] + ai[7];
        const float q3r = ar[3] - ar[7], q3i = ai[3] - ai[7];
        O0r = q0r + q2r; O0i = q0i + q2i;
        O2r = q0r - q2r; O2i = q0i - q2i;
        O1r = q1r + q3i; O1i = q1i - q3r;
        O3r = q1r - q3i; O3i = q1i + q3r;
    }

    const float S = 0.70710678118654752f;
    const float T0r = O0r,              T0i = O0i;
    const float T1r = S * (O1r + O1i),  T1i = S * (O1i - O1r);
    const float T2r = O2i,              T2i = -O2r;
    const float T3r = S * (O3i - O3r),  T3i = -S * (O3r + O3i);

    cx[p0 + 0 * EIGHTH * NCP] = make_float2(E0r + T0r, E0i + T0i);
    cx[p0 + 4 * EIGHTH * NCP] = make_float2(E0r - T0r, E0i - T0i);
    cx[p0 + 1 * EIGHTH * NCP] = make_float2(E1r + T1r, E1i + T1i);
    cx[p0 + 5 * EIGHTH * NCP] = make_float2(E1r - T1r, E1i - T1i);
    cx[p0 + 2 * EIGHTH * NCP] = make_float2(E2r + T2r, E2i + T2i);
    cx[p0 + 6 * EIGHTH * NCP] = make_float2(E2r - T2r, E2i - T2i);
    cx[p0 + 3 * EIGHTH * NCP] = make_float2(E3r + T3r, E3i + T3i);
    cx[p0 + 7 * EIGHTH * NCP] = make_float2(E3r - T3r, E3i - T3i);
}

// Kernel A: apodized zero-padded row FFT for ALL 8 batches of one y row
// (round-0 proven structure: 256 blocks x 512 threads).
// fp16 output G1h[(y*512+x)*8 + b] = half2(re,im).
__global__ __launch_bounds__(512) void rowfft_kernel(
    const float* __restrict__ xr, const float* __restrict__ xi,
    const float* __restrict__ sc_y, const float* __restrict__ sc_x,
    float4* __restrict__ G1h4)
{
    __shared__ float2 cx[512 * NCP];
    __shared__ float2 tw[512];
    const int t = threadIdx.x;
    const int y = blockIdx.x;

    {   // tw[m] = exp(-2*pi*i*m/512)
        float sn, cs;
        sincospif(-(float)t / 256.0f, &sn, &cs);
        tw[t] = make_float2(cs, sn);
    }

    const float sy = sc_y[y];
    {
        const int b = t >> 6;               // 0..7 (wave-uniform)
        const int x4 = (t & 63) << 2;       // 0..252 step 4
        const float4 vr = *(const float4*)(xr + b * (HD * WD) + y * WD + x4);
        const float4 vi = *(const float4*)(xi + b * (HD * WD) + y * WD + x4);
        const float4 sx = *(const float4*)(sc_x + x4);
        int p;
        float s;
        s = sy * sx.x; p = dr3(x4 + 0) * NCP + b; cx[p] = make_float2(vr.x * s, vi.x * s);
        s = sy * sx.y; p = dr3(x4 + 1) * NCP + b; cx[p] = make_float2(vr.y * s, vi.y * s);
        s = sy * sx.z; p = dr3(x4 + 2) * NCP + b; cx[p] = make_float2(vr.z * s, vi.z * s);
        s = sy * sx.w; p = dr3(x4 + 3) * NCP + b; cx[p] = make_float2(vr.w * s, vi.w * s);
        // upper half (x 256..511) structurally zero: never written, never read
        // (lands at positions p%... consumed only by the ZHI stage 1).
    }
    __syncthreads();
    r8_stage<8, 1, -1, true>(cx, tw, t);
    __syncthreads();
    r8_stage<64, 8, 3, false>(cx, tw, t);
    __syncthreads();
    r8_stage<512, 64, 0, false>(cx, tw, t);
    __syncthreads();

    // fp16 pack: row = 1024 float4; float4 f covers x = f>>1, batches (f&1)*4..+3.
    float4* dst = G1h4 + (size_t)y * 1024;
    #pragma unroll
    for (int iter = 0; iter < 2; ++iter) {
        const int f = iter * 512 + t;        // 0..1023
        const int x = f >> 1;
        const int b0 = (f & 1) * 4;
        const int p = x * NCP + b0;
        union { __half2 h[4]; float4 f4; } u;
        #pragma unroll
        for (int i = 0; i < 4; ++i) {
            const float2 v = cx[p + i];
            u.h[i] = __floats2half2_rn(v.x, v.y);
        }
        dst[f] = u.f4;
    }
}

// Kernel B: zero-padded column FFT for ALL 8 batches of one x column
// (round-0 proven structure: 512 blocks x 512 threads).
__global__ __launch_bounds__(512) void colfft_kernel(
    const float4* __restrict__ G1h4, float2* __restrict__ ghat_f2)
{
    __shared__ float2 cx[512 * NCP];
    __shared__ float2 tw[512];
    const int t = threadIdx.x;
    const int x = blockIdx.x;

    {
        float sn, cs;
        sincospif(-(float)t / 256.0f, &sn, &cs);
        tw[t] = make_float2(cs, sn);
    }

    {   // one float4 per thread: yy = t>>1 (0..255), slot = t&1 (batch half)
        const int yy = t >> 1;
        const int slot = t & 1;
        union { __half2 h[4]; float4 f4; } u;
        u.f4 = G1h4[(size_t)yy * 1024 + x * 2 + slot];
        const int p = dr3(yy) * NCP + slot * 4;
        #pragma unroll
        for (int i = 0; i < 4; ++i) {
            const float2 v = __half22float2(u.h[i]);
            cx[p + i] = v;
        }
        // y 256..511 structurally zero: never written (ZHI stage 1 skips).
    }
    __syncthreads();
    r8_stage<8, 1, -1, true>(cx, tw, t);
    __syncthreads();
    r8_stage<64, 8, 3, false>(cx, tw, t);
    __syncthreads();
    r8_stage<512, 64, 0, false>(cx, tw, t);
    __syncthreads();

    const float scale = 1.0f / 512.0f;       // ortho: 1/sqrt(512*512)
    #pragma unroll
    for (int iter = 0; iter < 4; ++iter) {
        const int if4 = iter * 512 + t;      // 0..2047
        const int yy = if4 >> 2;             // 0..511
        const int b = (if4 & 3) << 1;        // even batch of the pair
        const int p = yy * NCP + b;
        union { __half2 h[2]; float2 f; } u;
        const float2 v0 = cx[p];
        const float2 v1 = cx[p + 1];
        u.h[0] = __floats2half2_rn(v0.x * scale, v0.y * scale);
        u.h[1] = __floats2half2_rn(v1.x * scale, v1.y * scale);
        ghat_f2[((size_t)yy * GXD + x) * 4 + (b >> 1)] = u.f;
    }
}

// Kernel C: 7x7 KB gather. New mapping: 4 lanes/sample, 2 batches/lane via
// one 8B load per tap (float2 = 2 half2) -- halves VMEM instruction count and
// thread count at identical byte traffic and identical FMA ordering.
__global__ __launch_bounds__(256) void gather_kernel(
    const float2* __restrict__ gh2,
    const float* __restrict__ wy, const float* __restrict__ wx,
    const float* __restrict__ phr, const float* __restrict__ phi,
    const int* __restrict__ iy, const int* __restrict__ ix,
    float2* __restrict__ out)
{
    __shared__ int   s_iy[SPB * JD];
    __shared__ int   s_ix[SPB * JD];
    __shared__ float s_wy[SPB * JD];
    __shared__ float s_wx[SPB * JD];
    __shared__ float s_pr[SPB];
    __shared__ float s_pi[SPB];
    const int t = threadIdx.x;
    const int n0 = blockIdx.x * SPB;
    const int nrem = (NSAMP - n0 < SPB) ? (NSAMP - n0) : SPB;

    for (int idx = t; idx < nrem * JD; idx += 256) {   // coalesced tap staging
        const int g = n0 * JD + idx;
        s_iy[idx] = iy[g];
        s_ix[idx] = ix[g];
        s_wy[idx] = wy[g];
        s_wx[idx] = wx[g];
    }
    if (t < nrem) {
        s_pr[t] = phr[n0 + t];
        s_pi[t] = phi[n0 + t];
    }
    __syncthreads();

    const int q = t & 3;                     // batch pair (2q, 2q+1)
    const int s = t >> 2;                    // local sample 0..63
    if (s < nrem) {
        const int base = s * JD;

        int iyl[JD], ixl[JD];
        float wyl[JD], wxl[JD];
        #pragma unroll
        for (int j = 0; j < JD; ++j) {
            iyl[j] = s_iy[base + j];
            ixl[j] = s_ix[base + j];
            wyl[j] = s_wy[base + j];
            wxl[j] = s_wx[base + j];
        }

        float a0r = 0.0f, a0i = 0.0f, a1r = 0.0f, a1i = 0.0f;
        #pragma unroll
        for (int j = 0; j < JD; ++j) {
            const int rowoff = iyl[j] * GXD;
            const float wj = wyl[j];
            #pragma unroll
            for (int k = 0; k < JD; ++k) {
                const float w = wj * wxl[k];
                union { float2 f; __half2 h[2]; } u;
                u.f = gh2[(size_t)(rowoff + ixl[k]) * 4 + q];
                const float2 va = __half22float2(u.h[0]);
                const float2 vb = __half22float2(u.h[1]);
                a0r += va.x * w;
                a0i += va.y * w;
                a1r += vb.x * w;
                a1i += vb.y * w;
            }
        }

        const int n = n0 + s;
        const float pr = s_pr[s], pi = s_pi[s];
        out[(size_t)(2 * q) * NSAMP + n]     = make_float2(a0r * pr - a0i * pi,
                                                           a0r * pi + a0i * pr);
        out[(size_t)(2 * q + 1) * NSAMP + n] = make_float2(a1r * pr - a1i * pi,
                                                           a1r * pi + a1i * pr);
    }
}

extern "C" void kernel_launch(void* const* d_in, const int* in_sizes, int n_in,
                              void* d_out, int out_size, void* d_ws, size_t ws_size,
                              hipStream_t stream) {
    const float* xr   = (const float*)d_in[0];
    const float* xi   = (const float*)d_in[1];
    const float* sc_y = (const float*)d_in[2];
    const float* sc_x = (const float*)d_in[3];
    const float* wy   = (const float*)d_in[4];
    const float* wx   = (const float*)d_in[5];
    const float* phr  = (const float*)d_in[6];
    const float* phi  = (const float*)d_in[7];
    const int*   iy   = (const int*)d_in[8];
    const int*   ix   = (const int*)d_in[9];

    // Workspace: G1h fp16 (4.19 MB) | ghat fp16 (8.39 MB)
    char* ws = (char*)d_ws;
    float4* G1h4 = (float4*)ws;
    float2* gh   = (float2*)(ws + (size_t)HD * GXD * BD * sizeof(__half2));

    rowfft_kernel<<<HD, 512, 0, stream>>>(xr, xi, sc_y, sc_x, G1h4);
    colfft_kernel<<<GXD, 512, 0, stream>>>(G1h4, gh);
    gather_kernel<<<(NSAMP + SPB - 1) / SPB, 256, 0, stream>>>(
        (const float2*)gh, wy, wx, phr, phi, iy, ix, (float2*)d_out);
}

// Round 4
// 113.057 us; speedup vs baseline: 1.0427x; 1.0427x over previous
//
#include <hip/hip_runtime.h>
#include <hip/hip_fp16.h>

#define GYD 512
#define GXD 512
#define HD 256
#define WD 256
#define BD 8
#define NSAMP 100000
#define JD 7
#define NCP 9           // padded LDS stride (8 batch columns + 1)

// digit-reverse base 8, 3 digits (involution)
__device__ __forceinline__ int dr3(int i) {
    return ((i & 7) << 6) | (i & 56) | ((i >> 6) & 7);
}

// One radix-8 DIT stage over 8 interleaved 512-pt FFTs in LDS.
// ZHI: inputs j=4..7 are structurally zero (zero-padded upper half, only
// stage 1 sees them) -> read 4 points, specialized half-DFT.
template<int LEN, int EIGHTH, int TWSH, bool ZHI>
__device__ __forceinline__ void r8_stage(float* __restrict__ re, float* __restrict__ im,
                                         const float* __restrict__ twr,
                                         const float* __restrict__ twi, int g) {
    const int c = g & 7;
    const int m = g >> 3;
    const int off = m & (EIGHTH - 1);
    const int blk = m / EIGHTH;
    const int p0 = (blk * LEN + off) * NCP + c;

    float E0r, E0i, E1r, E1i, E2r, E2i, E3r, E3i;
    float O0r, O0i, O1r, O1i, O2r, O2i, O3r, O3i;

    if (ZHI) {
        // a4..a7 == 0: evens reduce to {a0,a2}, odds to {a1,a3}.
        const float a0r = re[p0 + 0 * EIGHTH * NCP], a0i = im[p0 + 0 * EIGHTH * NCP];
        const float a1r = re[p0 + 1 * EIGHTH * NCP], a1i = im[p0 + 1 * EIGHTH * NCP];
        const float a2r = re[p0 + 2 * EIGHTH * NCP], a2i = im[p0 + 2 * EIGHTH * NCP];
        const float a3r = re[p0 + 3 * EIGHTH * NCP], a3i = im[p0 + 3 * EIGHTH * NCP];
        E0r = a0r + a2r; E0i = a0i + a2i;
        E2r = a0r - a2r; E2i = a0i - a2i;
        E1r = a0r + a2i; E1i = a0i - a2r;     // a0 - i*a2
        E3r = a0r - a2i; E3i = a0i + a2r;     // a0 + i*a2
        O0r = a1r + a3r; O0i = a1i + a3i;
        O2r = a1r - a3r; O2i = a1i - a3i;
        O1r = a1r + a3i; O1i = a1i - a3r;     // a1 - i*a3
        O3r = a1r - a3i; O3i = a1i + a3r;     // a1 + i*a3
    } else {
        float ar[8], ai[8];
        #pragma unroll
        for (int j = 0; j < 8; ++j) {
            ar[j] = re[p0 + j * EIGHTH * NCP];
            ai[j] = im[p0 + j * EIGHTH * NCP];
        }
        if (TWSH >= 0) {
            #pragma unroll
            for (int j = 1; j < 8; ++j) {
                const int idx = (off * j) << (TWSH >= 0 ? TWSH : 0);
                const float cr = twr[idx], ci = twi[idx];
                const float tr = ar[j] * cr - ai[j] * ci;
                ai[j] = ar[j] * ci + ai[j] * cr;
                ar[j] = tr;
            }
        }
        const float e0r = ar[0] + ar[4], e0i = ai[0] + ai[4];
        const float e1r = ar[0] - ar[4], e1i = ai[0] - ai[4];
        const float e2r = ar[2] + ar[6], e2i = ai[2] + ai[6];
        const float e3r = ar[2] - ar[6], e3i = ai[2] - ai[6];
        E0r = e0r + e2r; E0i = e0i + e2i;
        E2r = e0r - e2r; E2i = e0i - e2i;
        E1r = e1r + e3i; E1i = e1i - e3r;     // e1 - i*e3
        E3r = e1r - e3i; E3i = e1i + e3r;     // e1 + i*e3

        const float q0r = ar[1] + ar[5], q0i = ai[1] + ai[5];
        const float q1r = ar[1] - ar[5], q1i = ai[1] - ai[5];
        const float q2r = ar[3] + ar[7], q2i = ai[3] + ai[7];
        const float q3r = ar[3] - ar[7], q3i = ai[3] - ai[7];
        O0r = q0r + q2r; O0i = q0i + q2i;
        O2r = q0r - q2r; O2i = q0i - q2i;
        O1r = q1r + q3i; O1i = q1i - q3r;
        O3r = q1r - q3i; O3i = q1i + q3r;
    }

    const float S = 0.70710678118654752f;
    const float T0r = O0r,              T0i = O0i;
    const float T1r = S * (O1r + O1i),  T1i = S * (O1i - O1r);
    const float T2r = O2i,              T2i = -O2r;
    const float T3r = S * (O3i - O3r),  T3i = -S * (O3r + O3i);

    re[p0 + 0 * EIGHTH * NCP] = E0r + T0r;  im[p0 + 0 * EIGHTH * NCP] = E0i + T0i;
    re[p0 + 4 * EIGHTH * NCP] = E0r - T0r;  im[p0 + 4 * EIGHTH * NCP] = E0i - T0i;
    re[p0 + 1 * EIGHTH * NCP] = E1r + T1r;  im[p0 + 1 * EIGHTH * NCP] = E1i + T1i;
    re[p0 + 5 * EIGHTH * NCP] = E1r - T1r;  im[p0 + 5 * EIGHTH * NCP] = E1i - T1i;
    re[p0 + 2 * EIGHTH * NCP] = E2r + T2r;  im[p0 + 2 * EIGHTH * NCP] = E2i + T2i;
    re[p0 + 6 * EIGHTH * NCP] = E2r - T2r;  im[p0 + 6 * EIGHTH * NCP] = E2i - T2i;
    re[p0 + 3 * EIGHTH * NCP] = E3r + T3r;  im[p0 + 3 * EIGHTH * NCP] = E3i + T3i;
    re[p0 + 7 * EIGHTH * NCP] = E3r - T3r;  im[p0 + 7 * EIGHTH * NCP] = E3i - T3i;
}

// Kernel A: apodized zero-padded row FFT for ALL 8 batches of one y row.
// ONE CHANGE vs the 112.9us round-0 kernel: output is x-major
// G1hT[(x*256+y)*8 + b] half2 -- the transpose scatter moves to the STORE
// side (fire-and-forget) so colfft's loads become fully coalesced.
__global__ __launch_bounds__(512) void rowfft_kernel(
    const float* __restrict__ xr, const float* __restrict__ xi,
    const float* __restrict__ sc_y, const float* __restrict__ sc_x,
    float4* __restrict__ G1h4)
{
    __shared__ float re[512 * NCP];
    __shared__ float im[512 * NCP];
    __shared__ float twr[512];
    __shared__ float twi[512];
    const int t = threadIdx.x;
    const int y = blockIdx.x;

    {   // tw[m] = exp(-2*pi*i*m/512)
        float sn, cs;
        sincospif(-(float)t / 256.0f, &sn, &cs);
        twr[t] = cs; twi[t] = sn;
    }

    const float sy = sc_y[y];
    {
        const int b = t >> 6;               // 0..7
        const int x4 = (t & 63) << 2;       // 0..252 step 4
        const float4 vr = *(const float4*)(xr + b * (HD * WD) + y * WD + x4);
        const float4 vi = *(const float4*)(xi + b * (HD * WD) + y * WD + x4);
        const float4 sx = *(const float4*)(sc_x + x4);
        int p;
        float s;
        s = sy * sx.x; p = dr3(x4 + 0) * NCP + b; re[p] = vr.x * s; im[p] = vi.x * s;
        s = sy * sx.y; p = dr3(x4 + 1) * NCP + b; re[p] = vr.y * s; im[p] = vi.y * s;
        s = sy * sx.z; p = dr3(x4 + 2) * NCP + b; re[p] = vr.z * s; im[p] = vi.z * s;
        s = sy * sx.w; p = dr3(x4 + 3) * NCP + b; re[p] = vr.w * s; im[p] = vi.w * s;
        // upper half (x 256..511) structurally zero: never written, never read
        // (lands at positions p&7 >= 4, consumed only by the ZHI stage 1).
    }
    __syncthreads();
    r8_stage<8, 1, -1, true>(re, im, twr, twi, t);
    __syncthreads();
    r8_stage<64, 8, 3, false>(re, im, twr, twi, t);
    __syncthreads();
    r8_stage<512, 64, 0, false>(re, im, twr, twi, t);
    __syncthreads();

    // fp16 pack, x-major: float4 index = x*512 + y*2 + slot.
    // Lane pairs (slot 0/1) write 32B contiguous; x-stride 8KB (scatter on
    // the store side only).
    #pragma unroll
    for (int iter = 0; iter < 2; ++iter) {
        const int f = iter * 512 + t;        // 0..1023
        const int x = f >> 1;
        const int slot = f & 1;
        const int b0 = slot * 4;
        const int p = x * NCP + b0;
        union { __half2 h[4]; float4 f4; } u;
        #pragma unroll
        for (int i = 0; i < 4; ++i)
            u.h[i] = __floats2half2_rn(re[p + i], im[p + i]);
        G1h4[(size_t)x * 512 + y * 2 + slot] = u.f4;
    }
}

// Kernel B: zero-padded column FFT for ALL 8 batches of one x column.
// Input now x-major: block x reads ONE contiguous 8KB run (perfectly
// coalesced) instead of 256 x 32B scattered segments.
__global__ __launch_bounds__(512) void colfft_kernel(
    const float4* __restrict__ G1h4, float2* __restrict__ ghat_f2)
{
    __shared__ float re[512 * NCP];
    __shared__ float im[512 * NCP];
    __shared__ float twr[512];
    __shared__ float twi[512];
    const int t = threadIdx.x;
    const int x = blockIdx.x;

    {
        float sn, cs;
        sincospif(-(float)t / 256.0f, &sn, &cs);
        twr[t] = cs; twi[t] = sn;
    }

    {   // one float4 per thread: yy = t>>1 (0..255), slot = t&1 (batch half)
        const int yy = t >> 1;
        const int slot = t & 1;
        union { __half2 h[4]; float4 f4; } u;
        u.f4 = G1h4[(size_t)x * 512 + yy * 2 + slot];
        const int p = dr3(yy) * NCP + slot * 4;
        #pragma unroll
        for (int i = 0; i < 4; ++i) {
            const float2 v = __half22float2(u.h[i]);
            re[p + i] = v.x;
            im[p + i] = v.y;
        }
        // y 256..511 structurally zero (positions p&7 >= 4): never written.
    }
    __syncthreads();
    r8_stage<8, 1, -1, true>(re, im, twr, twi, t);
    __syncthreads();
    r8_stage<64, 8, 3, false>(re, im, twr, twi, t);
    __syncthreads();
    r8_stage<512, 64, 0, false>(re, im, twr, twi, t);
    __syncthreads();

    const float scale = 1.0f / 512.0f;       // ortho: 1/sqrt(512*512)
    #pragma unroll
    for (int iter = 0; iter < 4; ++iter) {
        const int if4 = iter * 512 + t;      // 0..2047
        const int yy = if4 >> 2;             // 0..511
        const int b = (if4 & 3) << 1;        // even batch of the pair
        const int p = yy * NCP + b;
        union { __half2 h[2]; float2 f; } u;
        u.h[0] = __floats2half2_rn(re[p] * scale,     im[p] * scale);
        u.h[1] = __floats2half2_rn(re[p + 1] * scale, im[p + 1] * scale);
        ghat_f2[((size_t)yy * GXD + x) * 4 + (b >> 1)] = u.f;
    }
}

// Kernel C: 7x7 KB gather on fp16 interleaved ghat (round-0 EXACT: 8
// lanes/sample (lane=batch), half2 per tap, full 800k-thread TLP --
// previous-session ablated best; do not perturb).
__global__ __launch_bounds__(256) void gather_kernel(
    const __half2* __restrict__ gh,
    const float* __restrict__ wy, const float* __restrict__ wx,
    const float* __restrict__ phr, const float* __restrict__ phi,
    const int* __restrict__ iy, const int* __restrict__ ix,
    float2* __restrict__ out)
{
    __shared__ int   s_iy[32 * JD];
    __shared__ int   s_ix[32 * JD];
    __shared__ float s_wy[32 * JD];
    __shared__ float s_wx[32 * JD];
    __shared__ float s_pr[32];
    __shared__ float s_pi[32];
    const int t = threadIdx.x;
    const int n0 = blockIdx.x * 32;          // 3125 * 32 = 100000 exact

    if (t < 224) {                           // 32 samples x 7 taps, coalesced
        const int g = n0 * JD + t;
        s_iy[t] = iy[g];
        s_ix[t] = ix[g];
        s_wy[t] = wy[g];
        s_wx[t] = wx[g];
    } else {                                 // threads 224..255: phase
        const int s = t - 224;
        s_pr[s] = phr[n0 + s];
        s_pi[s] = phi[n0 + s];
    }
    __syncthreads();

    const int b = t & 7;
    const int s = t >> 3;                    // local sample 0..31
    const int base = s * JD;

    int iyl[JD], ixl[JD];
    float wyl[JD], wxl[JD];
    #pragma unroll
    for (int j = 0; j < JD; ++j) {
        iyl[j] = s_iy[base + j];
        ixl[j] = s_ix[base + j];
        wyl[j] = s_wy[base + j];
        wxl[j] = s_wx[base + j];
    }

    float ar = 0.0f, ai = 0.0f;
    #pragma unroll
    for (int j = 0; j < JD; ++j) {
        const int rowoff = iyl[j] * GXD;
        const float wj = wyl[j];
        #pragma unroll
        for (int k = 0; k < JD; ++k) {
            const float w = wj * wxl[k];
            const float2 v = __half22float2(gh[(size_t)(rowoff + ixl[k]) * BD + b]);
            ar += v.x * w;
            ai += v.y * w;
        }
    }

    const int n = n0 + s;
    const float pr = s_pr[s], pi = s_pi[s];
    out[(size_t)b * NSAMP + n] = make_float2(ar * pr - ai * pi,
                                             ar * pi + ai * pr);
}

extern "C" void kernel_launch(void* const* d_in, const int* in_sizes, int n_in,
                              void* d_out, int out_size, void* d_ws, size_t ws_size,
                              hipStream_t stream) {
    const float* xr   = (const float*)d_in[0];
    const float* xi   = (const float*)d_in[1];
    const float* sc_y = (const float*)d_in[2];
    const float* sc_x = (const float*)d_in[3];
    const float* wy   = (const float*)d_in[4];
    const float* wx   = (const float*)d_in[5];
    const float* phr  = (const float*)d_in[6];
    const float* phi  = (const float*)d_in[7];
    const int*   iy   = (const int*)d_in[8];
    const int*   ix   = (const int*)d_in[9];

    // Workspace: G1hT fp16 (4.19 MB, x-major) | ghat fp16 (8.39 MB)
    char* ws = (char*)d_ws;
    float4* G1h4 = (float4*)ws;
    float2* gh   = (float2*)(ws + (size_t)HD * GXD * BD * sizeof(__half2));

    rowfft_kernel<<<HD, 512, 0, stream>>>(xr, xi, sc_y, sc_x, G1h4);
    colfft_kernel<<<GXD, 512, 0, stream>>>(G1h4, gh);
    gather_kernel<<<NSAMP / 32, 256, 0, stream>>>(
        (const __half2*)gh, wy, wx, phr, phi, iy, ix, (float2*)d_out);
}